// Round 3
// baseline (422.069 us; speedup 1.0000x reference)
//
#include <hip/hip_runtime.h>

#define DEV __device__ __forceinline__

typedef __attribute__((ext_vector_type(8))) short short8;
typedef __attribute__((ext_vector_type(4))) float floatx4;
typedef __attribute__((ext_vector_type(4))) unsigned short ushort4v;
typedef __attribute__((ext_vector_type(8))) unsigned short ushort8v;

// ---------- sizes ----------
#define Bz 4096
#define Dz 256
#define Nz 128
#define Fz 128
#define Oz 256

// ---------- workspace layout (bytes) — total ~143.2 MB ----------
static constexpr size_t OFF_CONN = 0;                                   // 32 KB bf16 conn
static constexpr size_t OFF_WT   = 65536;                               // WT[n][c:128][k:384] bf16 (k: 0..127=W_s, 128..383=W_x)
static constexpr size_t SZ_WT    = (size_t)Nz * 128 * 384 * 2;          // 12582912
static constexpr size_t OFF_OWT  = OFF_WT + SZ_WT;                      // out_wT[o:256][f:128] bf16 (64 KB)
static constexpr size_t OFF_XB   = OFF_OWT + 65536;                     // x bf16 (4096x256, 2 MB)
static constexpr size_t OFF_FIN  = OFF_XB + (size_t)Bz * Dz * 2;        // final bf16 (4096x128, 1 MB)
static constexpr size_t OFF_ST   = OFF_FIN + (size_t)Bz * Fz * 2;       // state bf16 [n][b][f] (128 MB)

// ---------- helpers ----------
DEV unsigned short f2bf(float x) {
    unsigned u = __float_as_uint(x);
    u = (u + 0x7FFFu + ((u >> 16) & 1u)) >> 16;
    return (unsigned short)u;
}
DEV float bf2f(unsigned short h) {
    return __uint_as_float(((unsigned)h) << 16);
}

typedef const __attribute__((address_space(1))) void cglobal_void;
typedef __attribute__((address_space(3))) void lds_void;

DEV void gld_lds16(const void* g, void* l) {
    __builtin_amdgcn_global_load_lds((cglobal_void*)g, (lds_void*)l, 16, 0, 0);
}

// ---------- prep kernels ----------
__global__ __launch_bounds__(64) void k_softmax(const float* __restrict__ att,
                                                unsigned short* __restrict__ conn) {
    int i = blockIdx.x, t = threadIdx.x;
    float a0 = att[i * 128 + t];
    float a1 = att[i * 128 + 64 + t];
    float m = fmaxf(a0, a1);
    for (int o = 32; o > 0; o >>= 1) m = fmaxf(m, __shfl_down(m, o));
    m = __shfl(m, 0);
    float e0 = __expf(a0 - m), e1 = __expf(a1 - m);
    float s = e0 + e1;
    for (int o = 32; o > 0; o >>= 1) s += __shfl_down(s, o);
    s = __shfl(s, 0);
    float inv = 1.f / s;
    conn[i * 128 + t] = f2bf(e0 * inv);
    conn[i * 128 + 64 + t] = f2bf(e1 * inv);
}

// dst[batch][c][r] (bf16, ld R) = src[batch][r][c] (fp32, ld C). R,C multiples of 32.
__global__ __launch_bounds__(256) void k_transpose(const float* __restrict__ src,
                                                   unsigned short* __restrict__ dst,
                                                   int R, int C, int tilesC,
                                                   long sBatch, long dBatch) {
    __shared__ float ld[32][36];
    int tiles = (R / 32) * tilesC;
    int batch = blockIdx.x / tiles;
    int rem = blockIdx.x % tiles;
    int rt = rem / tilesC, ct = rem % tilesC;
    int t = threadIdx.x;
    int kr = t >> 3, c4 = (t & 7) * 4;
    float4 v = *(const float4*)&src[(size_t)batch * sBatch + (size_t)(rt * 32 + kr) * C + ct * 32 + c4];
    ld[kr][c4 + 0] = v.x; ld[kr][c4 + 1] = v.y; ld[kr][c4 + 2] = v.z; ld[kr][c4 + 3] = v.w;
    __syncthreads();
    int cr = kr, k4 = c4;
    ushort4v o;
    o[0] = f2bf(ld[k4 + 0][cr]);
    o[1] = f2bf(ld[k4 + 1][cr]);
    o[2] = f2bf(ld[k4 + 2][cr]);
    o[3] = f2bf(ld[k4 + 3][cr]);
    *(ushort4v*)&dst[(size_t)batch * dBatch + (size_t)(ct * 32 + cr) * R + rt * 32 + k4] = o;
}

__global__ __launch_bounds__(256) void k_convert(const float* __restrict__ src,
                                                 unsigned short* __restrict__ dst) {
    size_t idx = ((size_t)blockIdx.x * 256 + threadIdx.x) * 4;
    float4 v = *(const float4*)&src[idx];
    ushort4v o;
    o[0] = f2bf(v.x); o[1] = f2bf(v.y); o[2] = f2bf(v.z); o[3] = f2bf(v.w);
    *(ushort4v*)&dst[idx] = o;
}

// ---------- K2 (in-place): ST[i][b][f] = sum_j conn[i][j] * ST[j][b][f] ----------
// (unchanged this round — clean attribution of the k3 changes; k2 counters
//  should surface in top-5 next round)
__global__ __launch_bounds__(256) void k2_agg(const unsigned short* __restrict__ conn,
                                              unsigned short* __restrict__ ST) {
    __shared__ unsigned short lA[128 * 136];   // conn, padded rows; reused as out tile
    __shared__ unsigned short lB[2][32 * 128]; // double-buffered states tile [j][f]
    int b = blockIdx.x;
    int t = threadIdx.x, wid = t >> 6, lane = t & 63, q = lane >> 4, cc = lane & 15;
    int wm = (wid >> 1) << 6, wn = (wid & 1) << 6;

#pragma unroll
    for (int it = 0; it < 8; it++) {
        int g = it * 256 + t;
        int row = g >> 4, cg = g & 15;
        *(short8*)&lA[row * 136 + cg * 8] = *(const short8*)&conn[row * 128 + cg * 8];
    }
    floatx4 acc[4][4];
#pragma unroll
    for (int mt = 0; mt < 4; mt++)
#pragma unroll
        for (int nt = 0; nt < 4; nt++) acc[mt][nt] = (floatx4){0.f, 0.f, 0.f, 0.f};

    auto STG = [&](int bufi, int kt) {
#pragma unroll
        for (int it = 0; it < 2; it++) {
            int g = it * 256 + t;
            int j = g >> 4, fg = g & 15;
            int lofs = __builtin_amdgcn_readfirstlane((it * 256 + (wid << 6)) * 8);
            gld_lds16(ST + ((size_t)(kt * 32 + j) * Bz + b) * Fz + fg * 8, &lB[bufi][0] + lofs);
        }
    };
    STG(0, 0);
    STG(1, 1);

#pragma unroll
    for (int kt = 0; kt < 4; kt++) {
        int cur = kt & 1;
        if (kt < 3) asm volatile("s_waitcnt vmcnt(2) lgkmcnt(0)" ::: "memory");
        else        asm volatile("s_waitcnt vmcnt(0) lgkmcnt(0)" ::: "memory");
        __builtin_amdgcn_s_barrier();
        __builtin_amdgcn_sched_barrier(0);
        short8 af[4];
#pragma unroll
        for (int mt = 0; mt < 4; mt++)
            af[mt] = *(const short8*)&lA[(wm + mt * 16 + cc) * 136 + kt * 32 + q * 8];
        short8 bf[4];
#pragma unroll
        for (int nt = 0; nt < 4; nt++) {
            short8 v;
#pragma unroll
            for (int e = 0; e < 8; e++)
                v[e] = (short)lB[cur][(q * 8 + e) * 128 + wn + nt * 16 + cc];
            bf[nt] = v;
        }
#pragma unroll
        for (int mt = 0; mt < 4; mt++)
#pragma unroll
            for (int nt = 0; nt < 4; nt++)
                acc[mt][nt] = __builtin_amdgcn_mfma_f32_16x16x32_bf16(af[mt], bf[nt], acc[mt][nt], 0, 0, 0);
        __builtin_amdgcn_sched_barrier(0);
        __builtin_amdgcn_s_barrier();           // all waves done reading lB[cur]
        if (kt + 2 < 4) STG(cur, kt + 2);       // overwrite freed buffer
    }

    // epilogue: stage XOR-swizzled [i][f] tile in lA, then coalesced 16B row stores
#pragma unroll
    for (int mt = 0; mt < 4; mt++)
#pragma unroll
        for (int nt = 0; nt < 4; nt++) {
            int f = wn + nt * 16 + cc;
#pragma unroll
            for (int r = 0; r < 4; r++) {
                int il = wm + mt * 16 + q * 4 + r;
                lA[il * 128 + (f ^ ((il & 7) << 3))] = f2bf(acc[mt][nt][r]);
            }
        }
    __syncthreads();
#pragma unroll
    for (int it = 0; it < 8; it++) {
        int idx = it * 256 + t;
        int il = idx >> 4, ch = idx & 15;
        int sch = ch ^ (il & 7);
        ushort8v v = *(const ushort8v*)&lA[il * 128 + sch * 8];
        *(ushort8v*)&ST[((size_t)il * Bz + b) * Fz + ch * 8] = v;
    }
}

// ---------- K3 fused (in-place): ST[n] = relu([agg | x] @ W[n] + bias) ----------
// 256x128 b-tile, 512 threads (8 waves, 4m x 2n grid of 64x64 wave tiles).
// K-loop LDS tiles XOR-swizzled (slot ^= row&3) via pre-swizzled GLOBAL source
// for global_load_lds (linear LDS dest, rule: both-sides-or-neither) + swizzled
// ds_read slot — kills the 8-way bank conflict on the 64B-row fragment reads.
// Double-buffered, counted vmcnt(3): 3 gld/wave per stage stay in flight across
// both barriers. Epilogue: two 128-row halves staged in LDS, coalesced 16B stores.
// In-place safe: all ST reads (k-loop) precede all writes; blocks disjoint (n, bt).
template <int KT0>
__global__ __launch_bounds__(512) void k3_fused(unsigned short* __restrict__ ST,
                                                const unsigned short* __restrict__ XB,
                                                const unsigned short* __restrict__ WT,
                                                const float* __restrict__ nb) {
    // [buf]: A[256][32] (8192 sh) then B[128][32] (4096 sh) — 48 KB total
    __shared__ unsigned short lds[2][12288];
    int n = blockIdx.x >> 4, bt = blockIdx.x & 15;
    int t = threadIdx.x, wid = t >> 6, lane = t & 63, q = lane >> 4, cc = lane & 15;
    int wm = (wid >> 1) << 6, wn = (wid & 1) << 6;   // wm 0..192, wn 0/64

    const unsigned short* Sg = ST + ((size_t)n * Bz + bt * 256) * Fz;   // ld Fz
    const unsigned short* Xg = XB + (size_t)bt * 256 * Dz;              // ld Dz
    const unsigned short* Bg = WT + (size_t)n * 128 * 384;              // ld 384

    floatx4 acc[4][4];
#pragma unroll
    for (int mt = 0; mt < 4; mt++)
#pragma unroll
        for (int nt = 0; nt < 4; nt++) acc[mt][nt] = (floatx4){0.f, 0.f, 0.f, 0.f};

    // stage one K-step: A 256x32 (2 shots) + B 128x32 (1 shot); 3 gld/wave.
    // LDS dest linear; global source column pre-swizzled: slot kg holds G[row][kg^(row&3)]
    auto STAGE = [&](int bufi, int kt) {
#pragma unroll
        for (int it = 0; it < 2; it++) {
            int g = it * 512 + t;
            int row = g >> 2;
            int kgs = (g & 3) ^ (row & 3);
            int lofs = __builtin_amdgcn_readfirstlane((it * 512 + (wid << 6)) * 8);
            if (kt < 4)
                gld_lds16(Sg + (size_t)row * Fz + kt * 32 + kgs * 8, &lds[bufi][0] + lofs);
            else
                gld_lds16(Xg + (size_t)row * Dz + (kt - 4) * 32 + kgs * 8, &lds[bufi][0] + lofs);
        }
        {
            int row = t >> 2;
            int kgs = (t & 3) ^ (row & 3);
            int lofs = __builtin_amdgcn_readfirstlane(8192 + (wid << 6) * 8);
            gld_lds16(Bg + (size_t)row * 384 + kt * 32 + kgs * 8, &lds[bufi][0] + lofs);
        }
    };
    STAGE(0, KT0);
    STAGE(1, KT0 + 1);

    int sq = (q ^ (cc & 3)) * 8;   // swizzled 16B-slot offset (row&3 == cc&3 for all frags)

#pragma unroll
    for (int kt = KT0; kt < 12; kt++) {
        int cur = (kt - KT0) & 1;
        // oldest 3 gld (buffer cur) done; next stage's 3 stay in flight.
        if (kt < 11) asm volatile("s_waitcnt vmcnt(3) lgkmcnt(0)" ::: "memory");
        else         asm volatile("s_waitcnt vmcnt(0) lgkmcnt(0)" ::: "memory");
        __builtin_amdgcn_s_barrier();
        __builtin_amdgcn_sched_barrier(0);
        short8 af[4], bfr[4];
#pragma unroll
        for (int mt = 0; mt < 4; mt++)
            af[mt] = *(const short8*)&lds[cur][(wm + mt * 16 + cc) * 32 + sq];
#pragma unroll
        for (int nt = 0; nt < 4; nt++)
            bfr[nt] = *(const short8*)&lds[cur][8192 + (wn + nt * 16 + cc) * 32 + sq];
#pragma unroll
        for (int mt = 0; mt < 4; mt++)
#pragma unroll
            for (int nt = 0; nt < 4; nt++)
                acc[mt][nt] = __builtin_amdgcn_mfma_f32_16x16x32_bf16(af[mt], bfr[nt], acc[mt][nt], 0, 0, 0);
        __builtin_amdgcn_sched_barrier(0);
        __builtin_amdgcn_s_barrier();           // all waves done reading lds[cur]
        if (kt + 2 < 12) STAGE(cur, kt + 2);    // overwrite freed buffer
    }

    // epilogue: two 128-row halves. bias+relu -> XOR-swizzled [b_local][f] tile in
    // lds[0] (32 KB), then all 512 threads store coalesced 16B chunks (contiguous
    // 128x128 region of ST).
    unsigned short* outT = &lds[0][0];
    size_t base = ((size_t)n * Bz + (size_t)bt * 256) * Fz;
#pragma unroll
    for (int h = 0; h < 2; h++) {
        __syncthreads();
        if ((wm >> 7) == h) {
            int bl0 = wm & 127;
#pragma unroll
            for (int nt = 0; nt < 4; nt++) {
                int f = wn + nt * 16 + cc;
                float bias = nb[n * Fz + f];
#pragma unroll
                for (int mt = 0; mt < 4; mt++) {
#pragma unroll
                    for (int r = 0; r < 4; r++) {
                        int bl = bl0 + mt * 16 + q * 4 + r;
                        float v = acc[mt][nt][r] + bias;
                        outT[bl * 128 + (f ^ ((bl & 7) << 3))] = f2bf(v > 0.f ? v : 0.f);
                    }
                }
            }
        }
        __syncthreads();
#pragma unroll
        for (int it = 0; it < 4; it++) {
            int idx = it * 512 + t;
            int bl = idx >> 4, ch = idx & 15;
            int sch = ch ^ (bl & 7);
            ushort8v v = *(const ushort8v*)&outT[bl * 128 + sch * 8];
            *(ushort8v*)&ST[base + (size_t)h * 128 * Fz + (size_t)idx * 8] = v;
        }
    }
}

// ---------- K4: final[b][f] = mean_n ST[n][b][f] ----------
__global__ __launch_bounds__(256) void k4_mean(const unsigned short* __restrict__ S,
                                               unsigned short* __restrict__ fin) {
    int t = threadIdx.x;
    size_t base = (size_t)blockIdx.x * 2048 + (size_t)t * 8;
    float a[8] = {0.f, 0.f, 0.f, 0.f, 0.f, 0.f, 0.f, 0.f};
    for (int n = 0; n < Nz; n++) {
        ushort8v v = *(const ushort8v*)&S[(size_t)n * Bz * Fz + base];
#pragma unroll
        for (int e = 0; e < 8; e++) a[e] += bf2f(v[e]);
    }
    ushort8v o;
#pragma unroll
    for (int e = 0; e < 8; e++) o[e] = f2bf(a[e] * (1.f / 128.f));
    *(ushort8v*)&fin[base] = o;
}

// ---------- K5: out = final @ out_w + out_b (fp32 out) ----------
__global__ __launch_bounds__(256) void k5_out(const unsigned short* __restrict__ fin,
                                              const unsigned short* __restrict__ owt,
                                              const float* __restrict__ ob,
                                              float* __restrict__ out) {
    __shared__ unsigned short lA[128 * 32];
    __shared__ unsigned short lB[128 * 32];
    int bt = blockIdx.x >> 1, ct = blockIdx.x & 1;
    int t = threadIdx.x, wid = t >> 6, lane = t & 63, q = lane >> 4, cc = lane & 15;
    int wm = (wid >> 1) << 6, wn = (wid & 1) << 6;

    const unsigned short* Ag = fin + (size_t)bt * 128 * Fz;
    const unsigned short* Bg = owt + (size_t)ct * 128 * Fz;

    floatx4 acc[4][4];
#pragma unroll
    for (int mt = 0; mt < 4; mt++)
#pragma unroll
        for (int nt = 0; nt < 4; nt++) acc[mt][nt] = (floatx4){0.f, 0.f, 0.f, 0.f};

    for (int kt = 0; kt < 4; kt++) {
#pragma unroll
        for (int it = 0; it < 2; it++) {
            int g = it * 256 + t;
            int row = g >> 2, kg = g & 3;
            int lofs = __builtin_amdgcn_readfirstlane((it * 256 + (wid << 6)) * 8);
            gld_lds16(Ag + (size_t)row * Fz + kt * 32 + kg * 8, lA + lofs);
            gld_lds16(Bg + (size_t)row * Fz + kt * 32 + kg * 8, lB + lofs);
        }
        __syncthreads();
        short8 af[4], bfr[4];
#pragma unroll
        for (int mt = 0; mt < 4; mt++)
            af[mt] = *(const short8*)&lA[(wm + mt * 16 + cc) * 32 + q * 8];
#pragma unroll
        for (int nt = 0; nt < 4; nt++)
            bfr[nt] = *(const short8*)&lB[(wn + nt * 16 + cc) * 32 + q * 8];
#pragma unroll
        for (int mt = 0; mt < 4; mt++)
#pragma unroll
            for (int nt = 0; nt < 4; nt++)
                acc[mt][nt] = __builtin_amdgcn_mfma_f32_16x16x32_bf16(af[mt], bfr[nt], acc[mt][nt], 0, 0, 0);
        __syncthreads();
    }
#pragma unroll
    for (int nt = 0; nt < 4; nt++) {
        int o = ct * 128 + wn + nt * 16 + cc;
        float bias = ob[o];
#pragma unroll
        for (int mt = 0; mt < 4; mt++) {
#pragma unroll
            for (int r = 0; r < 4; r++) {
                int b = bt * 128 + wm + mt * 16 + q * 4 + r;
                out[(size_t)b * Oz + o] = acc[mt][nt][r] + bias;
            }
        }
    }
}

extern "C" void kernel_launch(void* const* d_in, const int* in_sizes, int n_in,
                              void* d_out, int out_size, void* d_ws, size_t ws_size,
                              hipStream_t stream) {
    const float* x = (const float*)d_in[0];
    const float* nw = (const float*)d_in[1];
    const float* nb = (const float*)d_in[2];
    const float* att = (const float*)d_in[3];
    const float* ow = (const float*)d_in[4];
    const float* ob = (const float*)d_in[5];
    char* ws = (char*)d_ws;
    unsigned short* CONN = (unsigned short*)(ws + OFF_CONN);
    unsigned short* WT = (unsigned short*)(ws + OFF_WT);
    unsigned short* OWT = (unsigned short*)(ws + OFF_OWT);
    unsigned short* XB = (unsigned short*)(ws + OFF_XB);
    unsigned short* FIN = (unsigned short*)(ws + OFF_FIN);
    unsigned short* ST = (unsigned short*)(ws + OFF_ST);
    float* out = (float*)d_out;

    // prep
    k_softmax<<<Nz, 64, 0, stream>>>(att, CONN);
    // WT[n][c:128][k:384] = nw[n][k][c]  (k: 0..127 = W_s rows, 128..383 = W_x rows)
    k_transpose<<<Nz * 48, 256, 0, stream>>>(nw, WT, 384, 128, 4, (long)384 * 128, (long)128 * 384);
    // OWT[o:256][f:128] = ow[f][o]
    k_transpose<<<32, 256, 0, stream>>>(ow, OWT, 128, 256, 8, 0, 0);
    k_convert<<<(Bz * Dz) / 1024, 256, 0, stream>>>(x, XB);

    // iteration 1: ST = relu(x @ W_x + b)   (state0 == 0 -> skip state k-steps)
    k3_fused<4><<<Nz * 16, 512, 0, stream>>>(ST, XB, WT, nb);

    // iterations 2 and 3: in-place agg then fused update
    for (int it = 0; it < 2; it++) {
        k2_agg<<<Bz, 256, 0, stream>>>(CONN, ST);
        k3_fused<0><<<Nz * 16, 512, 0, stream>>>(ST, XB, WT, nb);
    }

    k4_mean<<<(Bz * Fz) / 2048, 256, 0, stream>>>(ST, FIN);
    k5_out<<<64, 256, 0, stream>>>(FIN, OWT, ob, out);
}

// Round 4
// 404.039 us; speedup vs baseline: 1.0446x; 1.0446x over previous
//
#include <hip/hip_runtime.h>

#define DEV __device__ __forceinline__

typedef __attribute__((ext_vector_type(8))) short short8;
typedef __attribute__((ext_vector_type(4))) float floatx4;
typedef __attribute__((ext_vector_type(4))) unsigned short ushort4v;
typedef __attribute__((ext_vector_type(8))) unsigned short ushort8v;

// ---------- sizes ----------
#define Bz 4096
#define Dz 256
#define Nz 128
#define Fz 128
#define Oz 256

// ---------- workspace layout (bytes) — total ~143.2 MB ----------
static constexpr size_t OFF_CONN = 0;                                   // 32 KB bf16 conn
static constexpr size_t OFF_WT   = 65536;                               // WT[n][c:128][k:384] bf16 (k: 0..127=W_s, 128..383=W_x)
static constexpr size_t SZ_WT    = (size_t)Nz * 128 * 384 * 2;          // 12582912
static constexpr size_t OFF_OWT  = OFF_WT + SZ_WT;                      // out_wT[o:256][f:128] bf16 (64 KB)
static constexpr size_t OFF_XB   = OFF_OWT + 65536;                     // x bf16 (4096x256, 2 MB)
static constexpr size_t OFF_FIN  = OFF_XB + (size_t)Bz * Dz * 2;        // final bf16 (4096x128, 1 MB)
static constexpr size_t OFF_ST   = OFF_FIN + (size_t)Bz * Fz * 2;       // state bf16 [n][b][f] (128 MB)

// ---------- helpers ----------
DEV unsigned short f2bf(float x) {
    unsigned u = __float_as_uint(x);
    u = (u + 0x7FFFu + ((u >> 16) & 1u)) >> 16;
    return (unsigned short)u;
}
DEV float bf2f(unsigned short h) {
    return __uint_as_float(((unsigned)h) << 16);
}

typedef const __attribute__((address_space(1))) void cglobal_void;
typedef __attribute__((address_space(3))) void lds_void;

DEV void gld_lds16(const void* g, void* l) {
    __builtin_amdgcn_global_load_lds((cglobal_void*)g, (lds_void*)l, 16, 0, 0);
}

// ---------- prep kernels ----------
__global__ __launch_bounds__(64) void k_softmax(const float* __restrict__ att,
                                                unsigned short* __restrict__ conn) {
    int i = blockIdx.x, t = threadIdx.x;
    float a0 = att[i * 128 + t];
    float a1 = att[i * 128 + 64 + t];
    float m = fmaxf(a0, a1);
    for (int o = 32; o > 0; o >>= 1) m = fmaxf(m, __shfl_down(m, o));
    m = __shfl(m, 0);
    float e0 = __expf(a0 - m), e1 = __expf(a1 - m);
    float s = e0 + e1;
    for (int o = 32; o > 0; o >>= 1) s += __shfl_down(s, o);
    s = __shfl(s, 0);
    float inv = 1.f / s;
    conn[i * 128 + t] = f2bf(e0 * inv);
    conn[i * 128 + 64 + t] = f2bf(e1 * inv);
}

// dst[batch][c][r] (bf16, ld R) = src[batch][r][c] (fp32, ld C). R,C multiples of 32.
__global__ __launch_bounds__(256) void k_transpose(const float* __restrict__ src,
                                                   unsigned short* __restrict__ dst,
                                                   int R, int C, int tilesC,
                                                   long sBatch, long dBatch) {
    __shared__ float ld[32][36];
    int tiles = (R / 32) * tilesC;
    int batch = blockIdx.x / tiles;
    int rem = blockIdx.x % tiles;
    int rt = rem / tilesC, ct = rem % tilesC;
    int t = threadIdx.x;
    int kr = t >> 3, c4 = (t & 7) * 4;
    float4 v = *(const float4*)&src[(size_t)batch * sBatch + (size_t)(rt * 32 + kr) * C + ct * 32 + c4];
    ld[kr][c4 + 0] = v.x; ld[kr][c4 + 1] = v.y; ld[kr][c4 + 2] = v.z; ld[kr][c4 + 3] = v.w;
    __syncthreads();
    int cr = kr, k4 = c4;
    ushort4v o;
    o[0] = f2bf(ld[k4 + 0][cr]);
    o[1] = f2bf(ld[k4 + 1][cr]);
    o[2] = f2bf(ld[k4 + 2][cr]);
    o[3] = f2bf(ld[k4 + 3][cr]);
    *(ushort4v*)&dst[(size_t)batch * dBatch + (size_t)(ct * 32 + cr) * R + rt * 32 + k4] = o;
}

__global__ __launch_bounds__(256) void k_convert(const float* __restrict__ src,
                                                 unsigned short* __restrict__ dst) {
    size_t idx = ((size_t)blockIdx.x * 256 + threadIdx.x) * 4;
    float4 v = *(const float4*)&src[idx];
    ushort4v o;
    o[0] = f2bf(v.x); o[1] = f2bf(v.y); o[2] = f2bf(v.z); o[3] = f2bf(v.w);
    *(ushort4v*)&dst[idx] = o;
}

// ---------- K2 (in-place): ST[i][b][f] = sum_j conn[i][j] * ST[j][b][f] ----------
// Unchanged from round 2 (measured-good). Double-buffered lB, counted vmcnt(2);
// LDS-staged coalesced epilogue.
__global__ __launch_bounds__(256) void k2_agg(const unsigned short* __restrict__ conn,
                                              unsigned short* __restrict__ ST) {
    __shared__ unsigned short lA[128 * 136];   // conn, padded rows; reused as out tile
    __shared__ unsigned short lB[2][32 * 128]; // double-buffered states tile [j][f]
    int b = blockIdx.x;
    int t = threadIdx.x, wid = t >> 6, lane = t & 63, q = lane >> 4, cc = lane & 15;
    int wm = (wid >> 1) << 6, wn = (wid & 1) << 6;

#pragma unroll
    for (int it = 0; it < 8; it++) {
        int g = it * 256 + t;
        int row = g >> 4, cg = g & 15;
        *(short8*)&lA[row * 136 + cg * 8] = *(const short8*)&conn[row * 128 + cg * 8];
    }
    floatx4 acc[4][4];
#pragma unroll
    for (int mt = 0; mt < 4; mt++)
#pragma unroll
        for (int nt = 0; nt < 4; nt++) acc[mt][nt] = (floatx4){0.f, 0.f, 0.f, 0.f};

    auto STG = [&](int bufi, int kt) {
#pragma unroll
        for (int it = 0; it < 2; it++) {
            int g = it * 256 + t;
            int j = g >> 4, fg = g & 15;
            int lofs = __builtin_amdgcn_readfirstlane((it * 256 + (wid << 6)) * 8);
            gld_lds16(ST + ((size_t)(kt * 32 + j) * Bz + b) * Fz + fg * 8, &lB[bufi][0] + lofs);
        }
    };
    STG(0, 0);
    STG(1, 1);

#pragma unroll
    for (int kt = 0; kt < 4; kt++) {
        int cur = kt & 1;
        if (kt < 3) asm volatile("s_waitcnt vmcnt(2) lgkmcnt(0)" ::: "memory");
        else        asm volatile("s_waitcnt vmcnt(0) lgkmcnt(0)" ::: "memory");
        __builtin_amdgcn_s_barrier();
        __builtin_amdgcn_sched_barrier(0);
        short8 af[4];
#pragma unroll
        for (int mt = 0; mt < 4; mt++)
            af[mt] = *(const short8*)&lA[(wm + mt * 16 + cc) * 136 + kt * 32 + q * 8];
        short8 bf[4];
#pragma unroll
        for (int nt = 0; nt < 4; nt++) {
            short8 v;
#pragma unroll
            for (int e = 0; e < 8; e++)
                v[e] = (short)lB[cur][(q * 8 + e) * 128 + wn + nt * 16 + cc];
            bf[nt] = v;
        }
#pragma unroll
        for (int mt = 0; mt < 4; mt++)
#pragma unroll
            for (int nt = 0; nt < 4; nt++)
                acc[mt][nt] = __builtin_amdgcn_mfma_f32_16x16x32_bf16(af[mt], bf[nt], acc[mt][nt], 0, 0, 0);
        __builtin_amdgcn_sched_barrier(0);
        __builtin_amdgcn_s_barrier();           // all waves done reading lB[cur]
        if (kt + 2 < 4) STG(cur, kt + 2);       // overwrite freed buffer
    }

    // epilogue: stage XOR-swizzled [i][f] tile in lA, then coalesced 16B row stores
#pragma unroll
    for (int mt = 0; mt < 4; mt++)
#pragma unroll
        for (int nt = 0; nt < 4; nt++) {
            int f = wn + nt * 16 + cc;
#pragma unroll
            for (int r = 0; r < 4; r++) {
                int il = wm + mt * 16 + q * 4 + r;
                lA[il * 128 + (f ^ ((il & 7) << 3))] = f2bf(acc[mt][nt][r]);
            }
        }
    __syncthreads();
#pragma unroll
    for (int it = 0; it < 8; it++) {
        int idx = it * 256 + t;
        int il = idx >> 4, ch = idx & 15;
        int sch = ch ^ (il & 7);
        ushort8v v = *(const ushort8v*)&lA[il * 128 + sch * 8];
        *(ushort8v*)&ST[((size_t)il * Bz + b) * Fz + ch * 8] = v;
    }
}

// ---------- K3 fused (in-place): ST[n] = relu([agg | x] @ W[n] + bias) ----------
// Round-2 structure (128 b-tile, 256 thr) + 3-deep LDS pipeline: stage 2 K-steps
// ahead, steady-state vmcnt(8) — doubles the latency window vs 2-buffer.
// LDS 48 KB (3 blocks/CU max; measured residency was ~2.3, so not binding).
// In-place safe: all ST reads (k-loop) precede all writes; blocks disjoint (n, bt).
template <int KT0>
__global__ __launch_bounds__(256) void k3_fused(unsigned short* __restrict__ ST,
                                                const unsigned short* __restrict__ XB,
                                                const unsigned short* __restrict__ WT,
                                                const float* __restrict__ nb) {
    __shared__ unsigned short lds[3][2][128 * 32];  // [buf][A=0/B=1][row*32+k] — 48 KB
    int n = blockIdx.x >> 5, bt = blockIdx.x & 31;
    int t = threadIdx.x, wid = t >> 6, lane = t & 63, q = lane >> 4, cc = lane & 15;
    int wm = (wid >> 1) << 6, wn = (wid & 1) << 6;

    const unsigned short* Sg = ST + ((size_t)n * Bz + bt * 128) * Fz;   // ld Fz
    const unsigned short* Xg = XB + (size_t)bt * 128 * Dz;              // ld Dz
    const unsigned short* Bg = WT + (size_t)n * 128 * 384;              // ld 384

    floatx4 acc[4][4];
#pragma unroll
    for (int mt = 0; mt < 4; mt++)
#pragma unroll
        for (int nt = 0; nt < 4; nt++) acc[mt][nt] = (floatx4){0.f, 0.f, 0.f, 0.f};

    auto STAGE = [&](int bufi, int kt) {
#pragma unroll
        for (int it = 0; it < 2; it++) {
            int g = it * 256 + t;
            int row = g >> 2, kg = g & 3;
            int lofs = __builtin_amdgcn_readfirstlane((it * 256 + (wid << 6)) * 8);
            if (kt < 4)
                gld_lds16(Sg + (size_t)row * Fz + kt * 32 + kg * 8, &lds[bufi][0][0] + lofs);
            else
                gld_lds16(Xg + (size_t)row * Dz + (kt - 4) * 32 + kg * 8, &lds[bufi][0][0] + lofs);
            gld_lds16(Bg + (size_t)row * 384 + kt * 32 + kg * 8, &lds[bufi][1][0] + lofs);
        }
    };
    STAGE(0, KT0);
    STAGE(1, KT0 + 1);
    STAGE(2, KT0 + 2);

#pragma unroll
    for (int kt = KT0; kt < 12; kt++) {
        int cur = (kt - KT0) % 3;
        // in-flight before wait: stages {kt .. min(kt+2,11)}, 4 gld each.
        // wait until only the younger stages remain.
        if (kt < 10)      asm volatile("s_waitcnt vmcnt(8) lgkmcnt(0)" ::: "memory");
        else if (kt < 11) asm volatile("s_waitcnt vmcnt(4) lgkmcnt(0)" ::: "memory");
        else              asm volatile("s_waitcnt vmcnt(0) lgkmcnt(0)" ::: "memory");
        __builtin_amdgcn_s_barrier();
        __builtin_amdgcn_sched_barrier(0);
        short8 af[4], bfr[4];
#pragma unroll
        for (int mt = 0; mt < 4; mt++)
            af[mt] = *(const short8*)&lds[cur][0][(wm + mt * 16 + cc) * 32 + q * 8];
#pragma unroll
        for (int nt = 0; nt < 4; nt++)
            bfr[nt] = *(const short8*)&lds[cur][1][(wn + nt * 16 + cc) * 32 + q * 8];
#pragma unroll
        for (int mt = 0; mt < 4; mt++)
#pragma unroll
            for (int nt = 0; nt < 4; nt++)
                acc[mt][nt] = __builtin_amdgcn_mfma_f32_16x16x32_bf16(af[mt], bfr[nt], acc[mt][nt], 0, 0, 0);
        __builtin_amdgcn_sched_barrier(0);
        __builtin_amdgcn_s_barrier();           // all waves done reading lds[cur]
        if (kt + 3 < 12) STAGE(cur, kt + 3);    // overwrite freed buffer, 2 ahead
    }

    // epilogue: bias+relu → XOR-swizzled [b_local][f] tile (reuses lds buf 0),
    // then coalesced 16B contiguous stores (128x128 region is contiguous in ST).
    unsigned short* outT = &lds[0][0][0];
#pragma unroll
    for (int nt = 0; nt < 4; nt++) {
        int f = wn + nt * 16 + cc;
        float bias = nb[n * Fz + f];
#pragma unroll
        for (int mt = 0; mt < 4; mt++) {
#pragma unroll
            for (int r = 0; r < 4; r++) {
                int bl = wm + mt * 16 + q * 4 + r;
                float v = acc[mt][nt][r] + bias;
                outT[bl * 128 + (f ^ ((bl & 7) << 3))] = f2bf(v > 0.f ? v : 0.f);
            }
        }
    }
    __syncthreads();
    size_t base = ((size_t)n * Bz + (size_t)bt * 128) * Fz;
#pragma unroll
    for (int it = 0; it < 8; it++) {
        int idx = it * 256 + t;
        int bl = idx >> 4, ch = idx & 15;
        int sch = ch ^ (bl & 7);
        ushort8v v = *(const ushort8v*)&outT[bl * 128 + sch * 8];
        *(ushort8v*)&ST[base + (size_t)idx * 8] = v;
    }
}

// ---------- K4: final[b][f] = mean_n ST[n][b][f] ----------
__global__ __launch_bounds__(256) void k4_mean(const unsigned short* __restrict__ S,
                                               unsigned short* __restrict__ fin) {
    int t = threadIdx.x;
    size_t base = (size_t)blockIdx.x * 2048 + (size_t)t * 8;
    float a[8] = {0.f, 0.f, 0.f, 0.f, 0.f, 0.f, 0.f, 0.f};
    for (int n = 0; n < Nz; n++) {
        ushort8v v = *(const ushort8v*)&S[(size_t)n * Bz * Fz + base];
#pragma unroll
        for (int e = 0; e < 8; e++) a[e] += bf2f(v[e]);
    }
    ushort8v o;
#pragma unroll
    for (int e = 0; e < 8; e++) o[e] = f2bf(a[e] * (1.f / 128.f));
    *(ushort8v*)&fin[base] = o;
}

// ---------- K5: out = final @ out_w + out_b (fp32 out) ----------
__global__ __launch_bounds__(256) void k5_out(const unsigned short* __restrict__ fin,
                                              const unsigned short* __restrict__ owt,
                                              const float* __restrict__ ob,
                                              float* __restrict__ out) {
    __shared__ unsigned short lA[128 * 32];
    __shared__ unsigned short lB[128 * 32];
    int bt = blockIdx.x >> 1, ct = blockIdx.x & 1;
    int t = threadIdx.x, wid = t >> 6, lane = t & 63, q = lane >> 4, cc = lane & 15;
    int wm = (wid >> 1) << 6, wn = (wid & 1) << 6;

    const unsigned short* Ag = fin + (size_t)bt * 128 * Fz;
    const unsigned short* Bg = owt + (size_t)ct * 128 * Fz;

    floatx4 acc[4][4];
#pragma unroll
    for (int mt = 0; mt < 4; mt++)
#pragma unroll
        for (int nt = 0; nt < 4; nt++) acc[mt][nt] = (floatx4){0.f, 0.f, 0.f, 0.f};

    for (int kt = 0; kt < 4; kt++) {
#pragma unroll
        for (int it = 0; it < 2; it++) {
            int g = it * 256 + t;
            int row = g >> 2, kg = g & 3;
            int lofs = __builtin_amdgcn_readfirstlane((it * 256 + (wid << 6)) * 8);
            gld_lds16(Ag + (size_t)row * Fz + kt * 32 + kg * 8, lA + lofs);
            gld_lds16(Bg + (size_t)row * Fz + kt * 32 + kg * 8, lB + lofs);
        }
        __syncthreads();
        short8 af[4], bfr[4];
#pragma unroll
        for (int mt = 0; mt < 4; mt++)
            af[mt] = *(const short8*)&lA[(wm + mt * 16 + cc) * 32 + q * 8];
#pragma unroll
        for (int nt = 0; nt < 4; nt++)
            bfr[nt] = *(const short8*)&lB[(wn + nt * 16 + cc) * 32 + q * 8];
#pragma unroll
        for (int mt = 0; mt < 4; mt++)
#pragma unroll
            for (int nt = 0; nt < 4; nt++)
                acc[mt][nt] = __builtin_amdgcn_mfma_f32_16x16x32_bf16(af[mt], bfr[nt], acc[mt][nt], 0, 0, 0);
        __syncthreads();
    }
#pragma unroll
    for (int nt = 0; nt < 4; nt++) {
        int o = ct * 128 + wn + nt * 16 + cc;
        float bias = ob[o];
#pragma unroll
        for (int mt = 0; mt < 4; mt++) {
#pragma unroll
            for (int r = 0; r < 4; r++) {
                int b = bt * 128 + wm + mt * 16 + q * 4 + r;
                out[(size_t)b * Oz + o] = acc[mt][nt][r] + bias;
            }
        }
    }
}

extern "C" void kernel_launch(void* const* d_in, const int* in_sizes, int n_in,
                              void* d_out, int out_size, void* d_ws, size_t ws_size,
                              hipStream_t stream) {
    const float* x = (const float*)d_in[0];
    const float* nw = (const float*)d_in[1];
    const float* nb = (const float*)d_in[2];
    const float* att = (const float*)d_in[3];
    const float* ow = (const float*)d_in[4];
    const float* ob = (const float*)d_in[5];
    char* ws = (char*)d_ws;
    unsigned short* CONN = (unsigned short*)(ws + OFF_CONN);
    unsigned short* WT = (unsigned short*)(ws + OFF_WT);
    unsigned short* OWT = (unsigned short*)(ws + OFF_OWT);
    unsigned short* XB = (unsigned short*)(ws + OFF_XB);
    unsigned short* FIN = (unsigned short*)(ws + OFF_FIN);
    unsigned short* ST = (unsigned short*)(ws + OFF_ST);
    float* out = (float*)d_out;

    // prep
    k_softmax<<<Nz, 64, 0, stream>>>(att, CONN);
    // WT[n][c:128][k:384] = nw[n][k][c]  (k: 0..127 = W_s rows, 128..383 = W_x rows)
    k_transpose<<<Nz * 48, 256, 0, stream>>>(nw, WT, 384, 128, 4, (long)384 * 128, (long)128 * 384);
    // OWT[o:256][f:128] = ow[f][o]
    k_transpose<<<32, 256, 0, stream>>>(ow, OWT, 128, 256, 8, 0, 0);
    k_convert<<<(Bz * Dz) / 1024, 256, 0, stream>>>(x, XB);

    // iteration 1: ST = relu(x @ W_x + b)   (state0 == 0 -> skip state k-steps)
    k3_fused<4><<<Nz * 32, 256, 0, stream>>>(ST, XB, WT, nb);

    // iterations 2 and 3: in-place agg then fused update
    for (int it = 0; it < 2; it++) {
        k2_agg<<<Bz, 256, 0, stream>>>(CONN, ST);
        k3_fused<0><<<Nz * 32, 256, 0, stream>>>(ST, XB, WT, nb);
    }

    k4_mean<<<(Bz * Fz) / 2048, 256, 0, stream>>>(ST, FIN);
    k5_out<<<64, 256, 0, stream>>>(FIN, OWT, ob, out);
}

// Round 6
// 399.416 us; speedup vs baseline: 1.0567x; 1.0116x over previous
//
#include <hip/hip_runtime.h>

#define DEV __device__ __forceinline__

typedef __attribute__((ext_vector_type(8))) short short8;
typedef __attribute__((ext_vector_type(4))) float floatx4;
typedef __attribute__((ext_vector_type(4))) unsigned short ushort4v;
typedef __attribute__((ext_vector_type(8))) unsigned short ushort8v;

// ---------- sizes ----------
#define Bz 4096
#define Dz 256
#define Nz 128
#define Fz 128
#define Oz 256

// ---------- workspace layout (bytes) — total ~143.2 MB ----------
static constexpr size_t OFF_CONN = 0;                                   // 32 KB bf16 conn
static constexpr size_t OFF_WT   = 65536;                               // WT[n][c:128][k:384] bf16 (k: 0..127=W_s, 128..383=W_x)
static constexpr size_t SZ_WT    = (size_t)Nz * 128 * 384 * 2;          // 12582912
static constexpr size_t OFF_OWT  = OFF_WT + SZ_WT;                      // out_wT[o:256][f:128] bf16 (64 KB)
static constexpr size_t OFF_XB   = OFF_OWT + 65536;                     // x bf16 (4096x256, 2 MB)
static constexpr size_t OFF_FIN  = OFF_XB + (size_t)Bz * Dz * 2;        // final bf16 (4096x128, 1 MB)
static constexpr size_t OFF_ST   = OFF_FIN + (size_t)Bz * Fz * 2;       // state bf16 [n][b][f] (128 MB)

// ---------- helpers ----------
DEV unsigned short f2bf(float x) {
    unsigned u = __float_as_uint(x);
    u = (u + 0x7FFFu + ((u >> 16) & 1u)) >> 16;
    return (unsigned short)u;
}
DEV float bf2f(unsigned short h) {
    return __uint_as_float(((unsigned)h) << 16);
}

typedef const __attribute__((address_space(1))) void cglobal_void;
typedef __attribute__((address_space(3))) void lds_void;

DEV void gld_lds16(const void* g, void* l) {
    __builtin_amdgcn_global_load_lds((cglobal_void*)g, (lds_void*)l, 16, 0, 0);
}

// ---------- prep kernels ----------
__global__ __launch_bounds__(64) void k_softmax(const float* __restrict__ att,
                                                unsigned short* __restrict__ conn) {
    int i = blockIdx.x, t = threadIdx.x;
    float a0 = att[i * 128 + t];
    float a1 = att[i * 128 + 64 + t];
    float m = fmaxf(a0, a1);
    for (int o = 32; o > 0; o >>= 1) m = fmaxf(m, __shfl_down(m, o));
    m = __shfl(m, 0);
    float e0 = __expf(a0 - m), e1 = __expf(a1 - m);
    float s = e0 + e1;
    for (int o = 32; o > 0; o >>= 1) s += __shfl_down(s, o);
    s = __shfl(s, 0);
    float inv = 1.f / s;
    conn[i * 128 + t] = f2bf(e0 * inv);
    conn[i * 128 + 64 + t] = f2bf(e1 * inv);
}

// dst[batch][c][r] (bf16, ld R) = src[batch][r][c] (fp32, ld C). R,C multiples of 32.
__global__ __launch_bounds__(256) void k_transpose(const float* __restrict__ src,
                                                   unsigned short* __restrict__ dst,
                                                   int R, int C, int tilesC,
                                                   long sBatch, long dBatch) {
    __shared__ float ld[32][36];
    int tiles = (R / 32) * tilesC;
    int batch = blockIdx.x / tiles;
    int rem = blockIdx.x % tiles;
    int rt = rem / tilesC, ct = rem % tilesC;
    int t = threadIdx.x;
    int kr = t >> 3, c4 = (t & 7) * 4;
    float4 v = *(const float4*)&src[(size_t)batch * sBatch + (size_t)(rt * 32 + kr) * C + ct * 32 + c4];
    ld[kr][c4 + 0] = v.x; ld[kr][c4 + 1] = v.y; ld[kr][c4 + 2] = v.z; ld[kr][c4 + 3] = v.w;
    __syncthreads();
    int cr = kr, k4 = c4;
    ushort4v o;
    o[0] = f2bf(ld[k4 + 0][cr]);
    o[1] = f2bf(ld[k4 + 1][cr]);
    o[2] = f2bf(ld[k4 + 2][cr]);
    o[3] = f2bf(ld[k4 + 3][cr]);
    *(ushort4v*)&dst[(size_t)batch * dBatch + (size_t)(ct * 32 + cr) * R + rt * 32 + k4] = o;
}

__global__ __launch_bounds__(256) void k_convert(const float* __restrict__ src,
                                                 unsigned short* __restrict__ dst) {
    size_t idx = ((size_t)blockIdx.x * 256 + threadIdx.x) * 4;
    float4 v = *(const float4*)&src[idx];
    ushort4v o;
    o[0] = f2bf(v.x); o[1] = f2bf(v.y); o[2] = f2bf(v.z); o[3] = f2bf(v.w);
    *(ushort4v*)&dst[idx] = o;
}

// ---------- K2 (in-place): ST[i][b][f] = sum_j conn[i][j] * ST[j][b][f] ----------
// v2: B tile staged TRANSPOSED in LDS ([f][j], +34 pad) via global->reg->ds_write_b16,
// so B fragments are 4x ds_read_b128 instead of 128 scalar ds_read_u16 per wave.
// 3-stage register prefetch (loads for kt+2/kt+3 in flight during kt compute);
// ONE barrier per K-step (lgkmcnt(0)+s_barrier, vmcnt never drained in-loop).
// In-place safe: per block (one b), all ST reads precede all writes; blocks disjoint in b.
__global__ __launch_bounds__(256) void k2_agg(const unsigned short* __restrict__ conn,
                                              unsigned short* __restrict__ ST) {
    __shared__ unsigned short lA[128 * 136];    // conn, padded rows; reused as out tile
    __shared__ unsigned short lBT[2][128 * 34]; // transposed states tile [f][j], pad +2
    int b = blockIdx.x;
    int t = threadIdx.x, wid = t >> 6, lane = t & 63, q = lane >> 4, cc = lane & 15;
    int wm = (wid >> 1) << 6, wn = (wid & 1) << 6;

    // per-thread global chunks for one K-step tile (32 j x 128 f):
    // chunk g = it*256+t -> j = g>>4 (0..31), fg = g&15 (16B of f)
    int j0 = t >> 4, fg0 = t & 15;           // it = 0
    int j1 = (256 + t) >> 4, fg1 = t & 15;   // it = 1

    ushort8v R[4][2];
    auto LD = [&](int kt, ushort8v* dst) {
        dst[0] = *(const ushort8v*)(ST + ((size_t)(kt * 32 + j0) * Bz + b) * Fz + fg0 * 8);
        dst[1] = *(const ushort8v*)(ST + ((size_t)(kt * 32 + j1) * Bz + b) * Fz + fg1 * 8);
    };
    auto WR = [&](const ushort8v* src, unsigned short* buf) {
#pragma unroll
        for (int e = 0; e < 8; e++) buf[(fg0 * 8 + e) * 34 + j0] = src[0][e];
#pragma unroll
        for (int e = 0; e < 8; e++) buf[(fg1 * 8 + e) * 34 + j1] = src[1][e];
    };

    LD(0, R[0]);
    LD(1, R[1]);

    // conn -> lA (overlaps with load latency)
#pragma unroll
    for (int it = 0; it < 8; it++) {
        int g = it * 256 + t;
        int row = g >> 4, cg = g & 15;
        *(short8*)&lA[row * 136 + cg * 8] = *(const short8*)&conn[row * 128 + cg * 8];
    }

    floatx4 acc[4][4];
#pragma unroll
    for (int mt = 0; mt < 4; mt++)
#pragma unroll
        for (int nt = 0; nt < 4; nt++) acc[mt][nt] = (floatx4){0.f, 0.f, 0.f, 0.f};

    WR(R[0], &lBT[0][0]);      // compiler inserts counted vmcnt for R[0]
    LD(2, R[2]);
    asm volatile("s_waitcnt lgkmcnt(0)" ::: "memory");
    __builtin_amdgcn_s_barrier();
    __builtin_amdgcn_sched_barrier(0);

#pragma unroll
    for (int kt = 0; kt < 4; kt++) {
        int cur = kt & 1;
        short8 af[4], bfr[4];
#pragma unroll
        for (int mt = 0; mt < 4; mt++)
            af[mt] = *(const short8*)&lA[(wm + mt * 16 + cc) * 136 + kt * 32 + q * 8];
#pragma unroll
        for (int nt = 0; nt < 4; nt++)
            bfr[nt] = *(const short8*)&lBT[cur][(wn + nt * 16 + cc) * 34 + q * 8];
#pragma unroll
        for (int mt = 0; mt < 4; mt++)
#pragma unroll
            for (int nt = 0; nt < 4; nt++)
                acc[mt][nt] = __builtin_amdgcn_mfma_f32_16x16x32_bf16(af[mt], bfr[nt], acc[mt][nt], 0, 0, 0);
        if (kt + 1 < 4) {
            WR(R[kt + 1], &lBT[cur ^ 1][0]);   // buf[cur^1] last read in kt-1, safe
            if (kt + 3 < 4) LD(kt + 3, R[kt + 3]);
        }
        asm volatile("s_waitcnt lgkmcnt(0)" ::: "memory");  // my ds_writes drained
        __builtin_amdgcn_s_barrier();
        __builtin_amdgcn_sched_barrier(0);
    }

    // epilogue: stage XOR-swizzled [i][f] tile in lA, then coalesced 16B row stores
#pragma unroll
    for (int mt = 0; mt < 4; mt++)
#pragma unroll
        for (int nt = 0; nt < 4; nt++) {
            int f = wn + nt * 16 + cc;
#pragma unroll
            for (int r = 0; r < 4; r++) {
                int il = wm + mt * 16 + q * 4 + r;
                lA[il * 128 + (f ^ ((il & 7) << 3))] = f2bf(acc[mt][nt][r]);
            }
        }
    __syncthreads();
#pragma unroll
    for (int it = 0; it < 8; it++) {
        int idx = it * 256 + t;
        int il = idx >> 4, ch = idx & 15;
        int sch = ch ^ (il & 7);
        ushort8v v = *(const ushort8v*)&lA[il * 128 + sch * 8];
        *(ushort8v*)&ST[((size_t)il * Bz + b) * Fz + ch * 8] = v;
    }
}

// ---------- K3 fused (in-place): ST[n] = relu([agg | x] @ W[n] + bias) ----------
// Round-4 version: 3-deep LDS pipeline, counted vmcnt, coalesced LDS-staged epilogue.
template <int KT0>
__global__ __launch_bounds__(256) void k3_fused(unsigned short* __restrict__ ST,
                                                const unsigned short* __restrict__ XB,
                                                const unsigned short* __restrict__ WT,
                                                const float* __restrict__ nb) {
    __shared__ unsigned short lds[3][2][128 * 32];  // [buf][A=0/B=1][row*32+k] — 48 KB
    int n = blockIdx.x >> 5, bt = blockIdx.x & 31;
    int t = threadIdx.x, wid = t >> 6, lane = t & 63, q = lane >> 4, cc = lane & 15;
    int wm = (wid >> 1) << 6, wn = (wid & 1) << 6;

    const unsigned short* Sg = ST + ((size_t)n * Bz + bt * 128) * Fz;   // ld Fz
    const unsigned short* Xg = XB + (size_t)bt * 128 * Dz;              // ld Dz
    const unsigned short* Bg = WT + (size_t)n * 128 * 384;              // ld 384

    floatx4 acc[4][4];
#pragma unroll
    for (int mt = 0; mt < 4; mt++)
#pragma unroll
        for (int nt = 0; nt < 4; nt++) acc[mt][nt] = (floatx4){0.f, 0.f, 0.f, 0.f};

    auto STAGE = [&](int bufi, int kt) {
#pragma unroll
        for (int it = 0; it < 2; it++) {
            int g = it * 256 + t;
            int row = g >> 2, kg = g & 3;
            int lofs = __builtin_amdgcn_readfirstlane((it * 256 + (wid << 6)) * 8);
            if (kt < 4)
                gld_lds16(Sg + (size_t)row * Fz + kt * 32 + kg * 8, &lds[bufi][0][0] + lofs);
            else
                gld_lds16(Xg + (size_t)row * Dz + (kt - 4) * 32 + kg * 8, &lds[bufi][0][0] + lofs);
            gld_lds16(Bg + (size_t)row * 384 + kt * 32 + kg * 8, &lds[bufi][1][0] + lofs);
        }
    };
    STAGE(0, KT0);
    STAGE(1, KT0 + 1);
    STAGE(2, KT0 + 2);

#pragma unroll
    for (int kt = KT0; kt < 12; kt++) {
        int cur = (kt - KT0) % 3;
        if (kt < 10)      asm volatile("s_waitcnt vmcnt(8) lgkmcnt(0)" ::: "memory");
        else if (kt < 11) asm volatile("s_waitcnt vmcnt(4) lgkmcnt(0)" ::: "memory");
        else              asm volatile("s_waitcnt vmcnt(0) lgkmcnt(0)" ::: "memory");
        __builtin_amdgcn_s_barrier();
        __builtin_amdgcn_sched_barrier(0);
        short8 af[4], bfr[4];
#pragma unroll
        for (int mt = 0; mt < 4; mt++)
            af[mt] = *(const short8*)&lds[cur][0][(wm + mt * 16 + cc) * 32 + q * 8];
#pragma unroll
        for (int nt = 0; nt < 4; nt++)
            bfr[nt] = *(const short8*)&lds[cur][1][(wn + nt * 16 + cc) * 32 + q * 8];
#pragma unroll
        for (int mt = 0; mt < 4; mt++)
#pragma unroll
            for (int nt = 0; nt < 4; nt++)
                acc[mt][nt] = __builtin_amdgcn_mfma_f32_16x16x32_bf16(af[mt], bfr[nt], acc[mt][nt], 0, 0, 0);
        __builtin_amdgcn_sched_barrier(0);
        __builtin_amdgcn_s_barrier();           // all waves done reading lds[cur]
        if (kt + 3 < 12) STAGE(cur, kt + 3);    // overwrite freed buffer, 2 ahead
    }

    // epilogue: bias+relu → XOR-swizzled [b_local][f] tile (reuses lds buf 0),
    // then coalesced 16B contiguous stores (128x128 region is contiguous in ST).
    unsigned short* outT = &lds[0][0][0];
#pragma unroll
    for (int nt = 0; nt < 4; nt++) {
        int f = wn + nt * 16 + cc;
        float bias = nb[n * Fz + f];
#pragma unroll
        for (int mt = 0; mt < 4; mt++) {
#pragma unroll
            for (int r = 0; r < 4; r++) {
                int bl = wm + mt * 16 + q * 4 + r;
                float v = acc[mt][nt][r] + bias;
                outT[bl * 128 + (f ^ ((bl & 7) << 3))] = f2bf(v > 0.f ? v : 0.f);
            }
        }
    }
    __syncthreads();
    size_t base = ((size_t)n * Bz + (size_t)bt * 128) * Fz;
#pragma unroll
    for (int it = 0; it < 8; it++) {
        int idx = it * 256 + t;
        int bl = idx >> 4, ch = idx & 15;
        int sch = ch ^ (bl & 7);
        ushort8v v = *(const ushort8v*)&outT[bl * 128 + sch * 8];
        *(ushort8v*)&ST[base + (size_t)idx * 8] = v;
    }
}

// ---------- K4: final[b][f] = mean_n ST[n][b][f] ----------
__global__ __launch_bounds__(256) void k4_mean(const unsigned short* __restrict__ S,
                                               unsigned short* __restrict__ fin) {
    int t = threadIdx.x;
    size_t base = (size_t)blockIdx.x * 2048 + (size_t)t * 8;
    float a[8] = {0.f, 0.f, 0.f, 0.f, 0.f, 0.f, 0.f, 0.f};
#pragma unroll 8
    for (int n = 0; n < Nz; n++) {
        ushort8v v = *(const ushort8v*)&S[(size_t)n * Bz * Fz + base];
#pragma unroll
        for (int e = 0; e < 8; e++) a[e] += bf2f(v[e]);
    }
    ushort8v o;
#pragma unroll
    for (int e = 0; e < 8; e++) o[e] = f2bf(a[e] * (1.f / 128.f));
    *(ushort8v*)&fin[base] = o;
}

// ---------- K5: out = final @ out_w + out_b (fp32 out) ----------
__global__ __launch_bounds__(256) void k5_out(const unsigned short* __restrict__ fin,
                                              const unsigned short* __restrict__ owt,
                                              const float* __restrict__ ob,
                                              float* __restrict__ out) {
    __shared__ unsigned short lA[128 * 32];
    __shared__ unsigned short lB[128 * 32];
    int bt = blockIdx.x >> 1, ct = blockIdx.x & 1;
    int t = threadIdx.x, wid = t >> 6, lane = t & 63, q = lane >> 4, cc = lane & 15;
    int wm = (wid >> 1) << 6, wn = (wid & 1) << 6;

    const unsigned short* Ag = fin + (size_t)bt * 128 * Fz;
    const unsigned short* Bg = owt + (size_t)ct * 128 * Fz;

    floatx4 acc[4][4];
#pragma unroll
    for (int mt = 0; mt < 4; mt++)
#pragma unroll
        for (int nt = 0; nt < 4; nt++) acc[mt][nt] = (floatx4){0.f, 0.f, 0.f, 0.f};

    for (int kt = 0; kt < 4; kt++) {
#pragma unroll
        for (int it = 0; it < 2; it++) {
            int g = it * 256 + t;
            int row = g >> 2, kg = g & 3;
            int lofs = __builtin_amdgcn_readfirstlane((it * 256 + (wid << 6)) * 8);
            gld_lds16(Ag + (size_t)row * Fz + kt * 32 + kg * 8, lA + lofs);
            gld_lds16(Bg + (size_t)row * Fz + kt * 32 + kg * 8, lB + lofs);
        }
        __syncthreads();
        short8 af[4], bfr[4];
#pragma unroll
        for (int mt = 0; mt < 4; mt++)
            af[mt] = *(const short8*)&lA[(wm + mt * 16 + cc) * 32 + q * 8];
#pragma unroll
        for (int nt = 0; nt < 4; nt++)
            bfr[nt] = *(const short8*)&lB[(wn + nt * 16 + cc) * 32 + q * 8];
#pragma unroll
        for (int mt = 0; mt < 4; mt++)
#pragma unroll
            for (int nt = 0; nt < 4; nt++)
                acc[mt][nt] = __builtin_amdgcn_mfma_f32_16x16x32_bf16(af[mt], bfr[nt], acc[mt][nt], 0, 0, 0);
        __syncthreads();
    }
#pragma unroll
    for (int nt = 0; nt < 4; nt++) {
        int o = ct * 128 + wn + nt * 16 + cc;
        float bias = ob[o];
#pragma unroll
        for (int mt = 0; mt < 4; mt++) {
#pragma unroll
            for (int r = 0; r < 4; r++) {
                int b = bt * 128 + wm + mt * 16 + q * 4 + r;
                out[(size_t)b * Oz + o] = acc[mt][nt][r] + bias;
            }
        }
    }
}

extern "C" void kernel_launch(void* const* d_in, const int* in_sizes, int n_in,
                              void* d_out, int out_size, void* d_ws, size_t ws_size,
                              hipStream_t stream) {
    const float* x = (const float*)d_in[0];
    const float* nw = (const float*)d_in[1];
    const float* nb = (const float*)d_in[2];
    const float* att = (const float*)d_in[3];
    const float* ow = (const float*)d_in[4];
    const float* ob = (const float*)d_in[5];
    char* ws = (char*)d_ws;
    unsigned short* CONN = (unsigned short*)(ws + OFF_CONN);
    unsigned short* WT = (unsigned short*)(ws + OFF_WT);
    unsigned short* OWT = (unsigned short*)(ws + OFF_OWT);
    unsigned short* XB = (unsigned short*)(ws + OFF_XB);
    unsigned short* FIN = (unsigned short*)(ws + OFF_FIN);
    unsigned short* ST = (unsigned short*)(ws + OFF_ST);
    float* out = (float*)d_out;

    // prep
    k_softmax<<<Nz, 64, 0, stream>>>(att, CONN);
    // WT[n][c:128][k:384] = nw[n][k][c]  (k: 0..127 = W_s rows, 128..383 = W_x rows)
    k_transpose<<<Nz * 48, 256, 0, stream>>>(nw, WT, 384, 128, 4, (long)384 * 128, (long)128 * 384);
    // OWT[o:256][f:128] = ow[f][o]
    k_transpose<<<32, 256, 0, stream>>>(ow, OWT, 128, 256, 8, 0, 0);
    k_convert<<<(Bz * Dz) / 1024, 256, 0, stream>>>(x, XB);

    // iteration 1: ST = relu(x @ W_x + b)   (state0 == 0 -> skip state k-steps)
    k3_fused<4><<<Nz * 32, 256, 0, stream>>>(ST, XB, WT, nb);

    // iterations 2 and 3: in-place agg then fused update
    for (int it = 0; it < 2; it++) {
        k2_agg<<<Bz, 256, 0, stream>>>(CONN, ST);
        k3_fused<0><<<Nz * 32, 256, 0, stream>>>(ST, XB, WT, nb);
    }

    k4_mean<<<(Bz * Fz) / 2048, 256, 0, stream>>>(ST, FIN);
    k5_out<<<64, 256, 0, stream>>>(FIN, OWT, ob, out);
}